// Round 14
// baseline (583.668 us; speedup 1.0000x reference)
//
#include <hip/hip_runtime.h>
#include <math.h>

#define B_ 4
#define S_ 1024
#define IN_ 768
#define D_ 512
#define H_ 8
#define F_ 2048
#define E_ 8
#define KTOP_ 2
#define L_ 2
#define C_ 2
#define DH_ 64
#define T_ (B_*S_)   /* 4096 tokens */
#define EPS_ 1e-5f
#define LBW_ 0.01f
#define QLD_ (3*D_)  /* packed qkv row stride */
#define NBG_ (T_/256) /* gate blocks */
#define PSPL_ 16      /* pool S-splits */

typedef unsigned short u16;
typedef __attribute__((ext_vector_type(8))) unsigned short u16x8;
typedef __attribute__((ext_vector_type(4))) unsigned short u16x4;
typedef __attribute__((ext_vector_type(8))) short short8;
typedef __attribute__((ext_vector_type(4))) float f32x4;

__device__ __forceinline__ u16 f2b(float f) {
  union { float f; unsigned u; } v; v.f = f;
  const unsigned u = v.u;
  return (u16)((u + 0x7FFFu + ((u >> 16) & 1u)) >> 16);
}
__device__ __forceinline__ float b2f(u16 s) {
  union { unsigned u; float f; } v; v.u = ((unsigned)s) << 16;
  return v.f;
}

// async global->LDS, 16B per lane, LDS dest = wave-uniform base + lane*16
__device__ __forceinline__ void gl2lds16(const u16* g, u16* l) {
  __builtin_amdgcn_global_load_lds(
      (const __attribute__((address_space(1))) unsigned int*)g,
      (__attribute__((address_space(3))) unsigned int*)l, 16, 0, 0);
}

// ------------------------------------------------------------------
// Weight cast + transpose: W fp32 [K][N] -> WT bf16 [N][K], batched z.
// ------------------------------------------------------------------
__global__ __launch_bounds__(256) void castT(
    const float* __restrict__ W, u16* __restrict__ WT, int K, int N)
{
  __shared__ float tile[32][33];
  const size_t mo = (size_t)blockIdx.z * K * N;
  const int n0 = blockIdx.x * 32, k0 = blockIdx.y * 32;
  const int t = threadIdx.x;
  const int kr = t >> 3, nc4 = (t & 7) * 4;
  const float4 v = *(const float4*)(W + mo + (size_t)(k0 + kr) * N + n0 + nc4);
  tile[kr][nc4+0] = v.x; tile[kr][nc4+1] = v.y;
  tile[kr][nc4+2] = v.z; tile[kr][nc4+3] = v.w;
  __syncthreads();
  const int nr = t >> 3, kc4 = (t & 7) * 4;
  u16x4 o;
  #pragma unroll
  for (int i = 0; i < 4; ++i) o[i] = f2b(tile[kc4 + i][nr]);
  *(u16x4*)(WT + mo + (size_t)(n0 + nr) * K + k0 + kc4) = o;
}

// x fp32 -> bf16, elementwise (8/thread)
__global__ __launch_bounds__(256) void cast_x(
    const float* __restrict__ X, u16* __restrict__ Xb)
{
  const size_t i = ((size_t)blockIdx.x * 256 + threadIdx.x) * 8;
  const float4 a = *(const float4*)(X + i);
  const float4 b = *(const float4*)(X + i + 4);
  u16x8 o;
  o[0]=f2b(a.x); o[1]=f2b(a.y); o[2]=f2b(a.z); o[3]=f2b(a.w);
  o[4]=f2b(b.x); o[5]=f2b(b.y); o[6]=f2b(b.z); o[7]=f2b(b.w);
  *(u16x8*)(Xb + i) = o;
}

// ------------------------------------------------------------------
// MFMA GEMM: global_load_lds staging, 8-slot XOR-swizzled LDS, BK=64,
// DOUBLE-BUFFERED with counted vmcnt (T4): issue next-tile DMA, wait
// vmcnt(LPT) (own tile-t loads done; next stays in flight), raw
// s_barrier, MFMA cluster in setprio(1), raw s_barrier.
// C[M,N] = A[M,K](bf16) @ WT[N,K]^T + bias. BM=128, 4 waves (2x2).
// ------------------------------------------------------------------
template<int BN, int PE, int GELU, int WF32, int WBF16, int GATHER, int MOE>
__global__ __launch_bounds__(256) void gemm_gl(
    const u16* __restrict__ A, const u16* __restrict__ WTb,
    const float* __restrict__ biasb, float* __restrict__ Cf,
    u16* __restrict__ Cb, int N, int K,
    const int* __restrict__ idx_list, const int* __restrict__ offsets,
    const int* __restrict__ counts)
{
  constexpr int BM = 128;
  constexpr int MI = 4;            // 64 rows / 16
  constexpr int MJ = BN / 32;      // (BN/2) / 16
  constexpr int NIB = BN / 32;     // B glds per wave
  __shared__ __align__(16) u16 Atile[2][BM][64];
  __shared__ __align__(16) u16 Btile[2][BN][64];
  __shared__ int rowsrc[MOE ? BM : 1];

  const int tid = threadIdx.x;
  const int row0 = blockIdx.y * BM, col0 = blockIdx.x * BN;

  int cnt = 0, off = 0;
  const u16* WT = WTb;
  const float* bias = biasb;
  if constexpr (MOE) {
    const int e = blockIdx.z;
    cnt = counts[e];
    if (row0 >= cnt) return;               // uniform exit, pre-barrier
    off = offsets[e];
    WT  = WTb + (size_t)e * K * N;
    bias = biasb + (size_t)e * N;
    if (tid < BM) {
      const int rr = row0 + tid;
      rowsrc[tid] = (rr < cnt) ? (GATHER ? idx_list[off + rr] : (off + rr)) : 0;
    }
    __syncthreads();
  }

  const int w = tid >> 6, lane = tid & 63;
  const int q15 = lane & 15, g = lane >> 4;
  const int lrow8 = lane >> 3;                  // row within 8-row DMA chunk
  const int scol = ((lane & 7) ^ lrow8) * 8;    // pre-swizzled source col

  // per-lane staging source pointers
  const u16* aptr[4];
  #pragma unroll
  for (int t = 0; t < 4; ++t) {
    const int arow = w * 32 + t * 8 + lrow8;
    int grow;
    if constexpr (MOE) grow = rowsrc[arow];
    else               grow = row0 + arow;
    aptr[t] = A + (size_t)grow * K + scol;
  }
  const u16* bptr[NIB];
  #pragma unroll
  for (int t = 0; t < NIB; ++t) {
    const int brow = w * (BN / 4) + t * 8 + lrow8;
    bptr[t] = WT + (size_t)(col0 + brow) * K + scol;
  }

  const int ar0 = (w >> 1) * 64;
  const int bc0 = (w & 1) * (BN / 2);

  f32x4 acc[MI][MJ];
  #pragma unroll
  for (int i = 0; i < MI; ++i)
    #pragma unroll
    for (int j = 0; j < MJ; ++j) acc[i][j] = (f32x4){0.f, 0.f, 0.f, 0.f};

  auto STAGE = [&](int buf, int k0) {
    #pragma unroll
    for (int t = 0; t < 4; ++t)
      gl2lds16(aptr[t] + k0, &Atile[buf][w * 32 + t * 8][0]);
    #pragma unroll
    for (int t = 0; t < NIB; ++t)
      gl2lds16(bptr[t] + k0, &Btile[buf][w * (BN / 4) + t * 8][0]);
  };

  STAGE(0, 0);                        // prologue
  const int NT = K >> 6;
  for (int t = 0; t < NT; ++t) {
    const int cur = t & 1;
    if (t + 1 < NT) {
      STAGE(cur ^ 1, (t + 1) << 6);   // next tile -> other buffer
      // wait for tile t only (next tile's LPT loads stay in flight)
      if constexpr (BN == 128)
        asm volatile("s_waitcnt vmcnt(8)" ::: "memory");
      else
        asm volatile("s_waitcnt vmcnt(6)" ::: "memory");
    } else {
      asm volatile("s_waitcnt vmcnt(0)" ::: "memory");
    }
    __builtin_amdgcn_s_barrier();     // all waves: tile t resident
    __builtin_amdgcn_s_setprio(1);
    #pragma unroll
    for (int c = 0; c < 2; ++c) {
      const int ps = ((c * 4 + g) ^ (q15 & 7)) * 8;   // swizzled read slot
      short8 af[MI], bfv[MJ];
      #pragma unroll
      for (int i = 0; i < MI; ++i)
        af[i] = *(const short8*)&Atile[cur][ar0 + i * 16 + q15][ps];
      #pragma unroll
      for (int j = 0; j < MJ; ++j)
        bfv[j] = *(const short8*)&Btile[cur][bc0 + j * 16 + q15][ps];
      #pragma unroll
      for (int i = 0; i < MI; ++i)
        #pragma unroll
        for (int j = 0; j < MJ; ++j)
          acc[i][j] = __builtin_amdgcn_mfma_f32_16x16x32_bf16(af[i], bfv[j], acc[i][j], 0, 0, 0);
    }
    __builtin_amdgcn_s_setprio(0);
    __builtin_amdgcn_s_barrier();     // reads done before buf reuse
  }

  // ---- epilogue ----
  #pragma unroll
  for (int i = 0; i < MI; ++i) {
    #pragma unroll
    for (int r = 0; r < 4; ++r) {
      const int lrow = ar0 + i * 16 + g * 4 + r;
      if constexpr (MOE) {
        const int rr = row0 + lrow;
        if (rr >= cnt) continue;
        const size_t gidx = (size_t)off + rr;
        #pragma unroll
        for (int j = 0; j < MJ; ++j) {
          const int c = col0 + bc0 + j * 16 + q15;
          float vv = acc[i][j][r] + bias[c];
          if (GELU) vv = 0.5f * vv * (1.0f + erff(vv * 0.7071067811865475f));
          if (WF32) Cf[gidx * N + c] = vv;
          if (WBF16) Cb[gidx * N + c] = f2b(vv);
        }
      } else {
        const int row = row0 + lrow;
        #pragma unroll
        for (int j = 0; j < MJ; ++j) {
          const int c = col0 + bc0 + j * 16 + q15;
          float vv = acc[i][j][r] + bias[c];
          if (PE) {
            const float kfac = -0.03597789207803197f;  // -2*ln(10000)/512
            const float div = expf((float)(c >> 1) * kfac);
            const float ang = (float)(row & (S_ - 1)) * div;
            vv += (c & 1) ? cosf(ang) : sinf(ang);
          }
          if (WF32) Cf[(size_t)row * N + c] = vv;
          if (WBF16) Cb[(size_t)row * N + c] = f2b(vv);
        }
      }
    }
  }
}

// ------------------------------------------------------------------
// MFMA flash attention over packed qkv [T][1536]. grid (S/64, B*H).
// ------------------------------------------------------------------
__global__ __launch_bounds__(256) void attn_mfma(
    const u16* __restrict__ qkv, u16* __restrict__ og)
{
  __shared__ u16 Kl[32][72];
  __shared__ u16 VTl[64 * 34];
  const int qt = blockIdx.x;
  const int hh = blockIdx.y & 7, b = blockIdx.y >> 3;
  const int tid = threadIdx.x;
  const int w = tid >> 6, lane = tid & 63;
  const int g = lane >> 4, q15 = lane & 15;
  const int skv = tid >> 3, sd8 = (tid & 7) * 8;

  const size_t qrow = (size_t)(b * S_ + qt * 64 + w * 16 + q15) * QLD_ + hh * 64;
  const short8 qf0 = *(const short8*)(qkv + qrow + g * 8);
  const short8 qf1 = *(const short8*)(qkv + qrow + 32 + g * 8);

  f32x4 o0 = {0.f,0.f,0.f,0.f}, o1 = {0.f,0.f,0.f,0.f};
  f32x4 o2 = {0.f,0.f,0.f,0.f}, o3 = {0.f,0.f,0.f,0.f};
  float m = -1e30f, l = 0.f;

  for (int c0 = 0; c0 < S_; c0 += 32) {
    const size_t srow = (size_t)(b * S_ + c0 + skv) * QLD_ + hh * 64 + sd8;
    const u16x8 kv8 = *(const u16x8*)(qkv + srow + D_);
    const u16x8 vv8 = *(const u16x8*)(qkv + srow + 2 * D_);
    *(u16x8*)&Kl[skv][sd8] = kv8;
    #pragma unroll
    for (int j = 0; j < 8; ++j) {
      const int d = sd8 + j;
      const int kvp = skv ^ (((d >> 5) & 1) << 3);   // bank-decorrelated slot
      VTl[d * 34 + kvp] = vv8[j];
    }
    __syncthreads();

    f32x4 st0 = {0.f,0.f,0.f,0.f}, st1 = {0.f,0.f,0.f,0.f};
    {
      const short8 kf00 = *(const short8*)&Kl[q15][g * 8];
      const short8 kf01 = *(const short8*)&Kl[q15][32 + g * 8];
      const short8 kf10 = *(const short8*)&Kl[16 + q15][g * 8];
      const short8 kf11 = *(const short8*)&Kl[16 + q15][32 + g * 8];
      st0 = __builtin_amdgcn_mfma_f32_16x16x32_bf16(kf00, qf0, st0, 0, 0, 0);
      st0 = __builtin_amdgcn_mfma_f32_16x16x32_bf16(kf01, qf1, st0, 0, 0, 0);
      st1 = __builtin_amdgcn_mfma_f32_16x16x32_bf16(kf10, qf0, st1, 0, 0, 0);
      st1 = __builtin_amdgcn_mfma_f32_16x16x32_bf16(kf11, qf1, st1, 0, 0, 0);
    }

    float s0[4], s1[4];
    #pragma unroll
    for (int r = 0; r < 4; ++r) { s0[r] = st0[r] * 0.125f; s1[r] = st1[r] * 0.125f; }
    float cm = s0[0];
    #pragma unroll
    for (int r = 1; r < 4; ++r) cm = fmaxf(cm, s0[r]);
    #pragma unroll
    for (int r = 0; r < 4; ++r) cm = fmaxf(cm, s1[r]);
    cm = fmaxf(cm, __shfl_xor(cm, 16));
    cm = fmaxf(cm, __shfl_xor(cm, 32));
    const float mn = fmaxf(m, cm);
    const float rsc = __expf(m - mn);
    m = mn;
    float p0[4], p1[4];
    float rs = 0.f;
    #pragma unroll
    for (int r = 0; r < 4; ++r) { p0[r] = __expf(s0[r] - mn); rs += p0[r]; }
    #pragma unroll
    for (int r = 0; r < 4; ++r) { p1[r] = __expf(s1[r] - mn); rs += p1[r]; }
    rs += __shfl_xor(rs, 16);
    rs += __shfl_xor(rs, 32);
    l = l * rsc + rs;

    float rq[4];
    #pragma unroll
    for (int r = 0; r < 4; ++r) rq[r] = __shfl(rsc, 4 * g + r);
    #pragma unroll
    for (int r = 0; r < 4; ++r) {
      o0[r] *= rq[r]; o1[r] *= rq[r]; o2[r] *= rq[r]; o3[r] *= rq[r];
    }

    // pack (p0[r], p1[r]) -> bf16x2 once, shuffle the packed word (8 shfl)
    unsigned pk[4];
    #pragma unroll
    for (int r = 0; r < 4; ++r)
      asm("v_cvt_pk_bf16_f32 %0, %1, %2" : "=v"(pk[r]) : "v"(p0[r]), "v"(p1[r]));
    u16x8 pf;
    #pragma unroll
    for (int j = 0; j < 8; ++j) {
      const int src = q15 + 16 * ((j >> 2) + 2 * (g & 1));
      const unsigned pv = (unsigned)__shfl((int)pk[j & 3], src);
      pf[j] = (g >= 2) ? (u16)(pv >> 16) : (u16)(pv & 0xffffu);
    }
    const short8 pfs = *(const short8*)&pf;

    #pragma unroll
    for (int dt = 0; dt < 4; ++dt) {
      const int gsw = g ^ (dt >> 1);                 // read-side inverse swizzle
      const u16* vp = &VTl[(dt * 16 + q15) * 34 + 8 * gsw];
      union { unsigned u[4]; short8 s8; } yv;
      yv.u[0] = *(const unsigned*)(vp + 0);
      yv.u[1] = *(const unsigned*)(vp + 2);
      yv.u[2] = *(const unsigned*)(vp + 4);
      yv.u[3] = *(const unsigned*)(vp + 6);
      if (dt == 0) o0 = __builtin_amdgcn_mfma_f32_16x16x32_bf16(pfs, yv.s8, o0, 0, 0, 0);
      if (dt == 1) o1 = __builtin_amdgcn_mfma_f32_16x16x32_bf16(pfs, yv.s8, o1, 0, 0, 0);
      if (dt == 2) o2 = __builtin_amdgcn_mfma_f32_16x16x32_bf16(pfs, yv.s8, o2, 0, 0, 0);
      if (dt == 3) o3 = __builtin_amdgcn_mfma_f32_16x16x32_bf16(pfs, yv.s8, o3, 0, 0, 0);
    }
    __syncthreads();
  }

  const float linv = 1.0f / l;
  float lq[4];
  #pragma unroll
  for (int r = 0; r < 4; ++r) lq[r] = __shfl(linv, 4 * g + r);
  #pragma unroll
  for (int r = 0; r < 4; ++r) {
    const size_t tok = (size_t)(b * S_ + qt * 64 + w * 16 + 4 * g + r);
    u16* orow = og + tok * D_ + hh * 64 + q15;
    orow[0]  = f2b(o0[r] * lq[r]);
    orow[16] = f2b(o1[r] * lq[r]);
    orow[32] = f2b(o2[r] * lq[r]);
    orow[48] = f2b(o3[r] * lq[r]);
  }
}

__device__ __forceinline__ void load8(const float* p, float* a) {
  const float4 v0 = *(const float4*)p;
  const float4 v1 = *(const float4*)(p + 4);
  a[0]=v0.x; a[1]=v0.y; a[2]=v0.z; a[3]=v0.w;
  a[4]=v1.x; a[5]=v1.y; a[6]=v1.z; a[7]=v1.w;
}

// ------------------------------------------------------------------
// Fused residual + LayerNorm, in-place on h; also emits bf16 h.
// ------------------------------------------------------------------
template<int MODE>
__global__ __launch_bounds__(64) void ln_kernel(
    float* __restrict__ h, u16* __restrict__ hb,
    const float* __restrict__ add,
    const float* __restrict__ ebuf, const int* __restrict__ pos_tk,
    const float* __restrict__ topw,
    const float* __restrict__ sc, const float* __restrict__ bi)
{
  const int t = blockIdx.x;
  const int lane = threadIdx.x;
  const int d0 = lane * 8;
  float* hrow = h + (size_t)t * D_;
  float x[8];
  load8(hrow + d0, x);
  if (MODE == 0) {
    float a[8]; load8(add + (size_t)t * D_ + d0, a);
    #pragma unroll
    for (int i = 0; i < 8; ++i) x[i] += a[i];
  } else {
    const float w0 = topw[2*t], w1 = topw[2*t+1];
    const int p0 = pos_tk[2*t], p1 = pos_tk[2*t+1];
    float a[8], b[8];
    load8(ebuf + (size_t)p0 * D_ + d0, a);
    load8(ebuf + (size_t)p1 * D_ + d0, b);
    #pragma unroll
    for (int i = 0; i < 8; ++i) x[i] += w0 * a[i] + w1 * b[i];
  }
  float s = 0.f, ss = 0.f;
  #pragma unroll
  for (int i = 0; i < 8; ++i) { s += x[i]; ss += x[i] * x[i]; }
  #pragma unroll
  for (int off = 32; off > 0; off >>= 1) {
    s  += __shfl_xor(s,  off);
    ss += __shfl_xor(ss, off);
  }
  const float mu = s * (1.f / D_);
  const float var = ss * (1.f / D_) - mu * mu;
  const float rstd = rsqrtf(var + EPS_);
  float g[8], be[8];
  load8(sc + d0, g); load8(bi + d0, be);
  float y[8];
  #pragma unroll
  for (int i = 0; i < 8; ++i) y[i] = (x[i] - mu) * rstd * g[i] + be[i];
  float4 oo0, oo1;
  oo0.x=y[0]; oo0.y=y[1]; oo0.z=y[2]; oo0.w=y[3];
  oo1.x=y[4]; oo1.y=y[5]; oo1.z=y[6]; oo1.w=y[7];
  *(float4*)(hrow + d0) = oo0;
  *(float4*)(hrow + d0 + 4) = oo1;
  u16x8 ob;
  #pragma unroll
  for (int i = 0; i < 8; ++i) ob[i] = f2b(y[i]);
  *(u16x8*)(hb + (size_t)t * D_ + d0) = ob;
}

// ------------------------------------------------------------------
// Gate (fp32): softmax over E, top-2, renorm; per-block partials.
// ------------------------------------------------------------------
__global__ __launch_bounds__(256) void gate_kernel(
    const float* __restrict__ h, const float* __restrict__ gw,
    const float* __restrict__ gb,
    int* __restrict__ top_i, float* __restrict__ top_w,
    int* __restrict__ counts_p, float* __restrict__ routing_p)
{
  __shared__ float s_rout[E_];
  __shared__ int s_cnt[E_];
  const int tid = threadIdx.x;
  if (tid < E_) { s_rout[tid] = 0.f; s_cnt[tid] = 0; }
  __syncthreads();
  const int t = blockIdx.x * 256 + tid;
  const float* xr = h + (size_t)t * D_;
  float logit[E_] = {};
  for (int d = 0; d < D_; d += 4) {
    const float4 xv = *(const float4*)(xr + d);
    const float xs[4] = {xv.x, xv.y, xv.z, xv.w};
    #pragma unroll
    for (int i = 0; i < 4; ++i)
      #pragma unroll
      for (int e = 0; e < E_; ++e)
        logit[e] = fmaf(xs[i], gw[(size_t)(d+i) * E_ + e], logit[e]);
  }
  float mx = -1e30f;
  #pragma unroll
  for (int e = 0; e < E_; ++e) { logit[e] += gb[e]; mx = fmaxf(mx, logit[e]); }
  float p[E_]; float sum = 0.f;
  #pragma unroll
  for (int e = 0; e < E_; ++e) { p[e] = expf(logit[e] - mx); sum += p[e]; }
  const float inv = 1.0f / sum;
  #pragma unroll
  for (int e = 0; e < E_; ++e) p[e] *= inv;
  int i0 = 0; float v0 = p[0];
  #pragma unroll
  for (int e = 1; e < E_; ++e) if (p[e] > v0) { v0 = p[e]; i0 = e; }
  int i1 = -1; float v1 = -1.f;
  #pragma unroll
  for (int e = 0; e < E_; ++e) if (e != i0 && p[e] > v1) { v1 = p[e]; i1 = e; }
  const float sw = 1.0f / (v0 + v1);
  top_i[2*t] = i0; top_i[2*t+1] = i1;
  top_w[2*t] = v0 * sw; top_w[2*t+1] = v1 * sw;
  atomicAdd(&s_cnt[i0], 1); atomicAdd(&s_cnt[i1], 1);
  #pragma unroll
  for (int e = 0; e < E_; ++e) atomicAdd(&s_rout[e], p[e]);
  __syncthreads();
  if (tid < E_) {
    counts_p[blockIdx.x * E_ + tid] = s_cnt[tid];
    routing_p[blockIdx.x * E_ + tid] = s_rout[tid];
  }
}

// scan: totals, expert offsets, per-block bases, aux. 1 thread.
__global__ void gate_scan(
    const int* __restrict__ counts_p, const float* __restrict__ routing_p,
    int* __restrict__ counts, int* __restrict__ offsets,
    int* __restrict__ blk_base, float* __restrict__ aux_acc, int first)
{
  if (threadIdx.x == 0) {
    int cnt[E_]; float rout[E_];
    for (int e = 0; e < E_; ++e) { cnt[e] = 0; rout[e] = 0.f; }
    for (int b = 0; b < NBG_; ++b)
      for (int e = 0; e < E_; ++e) {
        cnt[e] += counts_p[b * E_ + e];
        rout[e] += routing_p[b * E_ + e];
      }
    int off = 0; float aux = 0.f;
    int run[E_];
    for (int e = 0; e < E_; ++e) {
      counts[e] = cnt[e];
      offsets[e] = off; run[e] = off; off += cnt[e];
      aux += ((float)cnt[e] / (float)(T_ * KTOP_)) * (rout[e] / (float)T_);
    }
    for (int b = 0; b < NBG_; ++b)
      for (int e = 0; e < E_; ++e) {
        blk_base[b * E_ + e] = run[e];
        run[e] += counts_p[b * E_ + e];
      }
    const float v = (float)E_ * aux;
    *aux_acc = first ? v : (*aux_acc + v);
  }
}

// fill: rank within block via LDS atomics + per-block base (no global atomics)
__global__ __launch_bounds__(256) void gate_fill(
    const int* __restrict__ top_i, const int* __restrict__ blk_base,
    int* __restrict__ idx_list, int* __restrict__ pos_tk)
{
  __shared__ int s_cur[E_];
  const int tid = threadIdx.x;
  if (tid < E_) s_cur[tid] = 0;
  __syncthreads();
  const int t = blockIdx.x * 256 + tid;
  const int e0 = top_i[2*t], e1 = top_i[2*t+1];
  const int r0 = atomicAdd(&s_cur[e0], 1);
  const int r1 = atomicAdd(&s_cur[e1], 1);
  const int g0 = blk_base[blockIdx.x * E_ + e0] + r0;
  const int g1 = blk_base[blockIdx.x * E_ + e1] + r1;
  idx_list[g0] = t; pos_tk[2*t]   = g0;
  idx_list[g1] = t; pos_tk[2*t+1] = g1;
}

// ------------------------------------------------------------------
// Mean-pool stage 1: grid (D/64, B, PSPL_); each block sums 64 S-rows.
// ------------------------------------------------------------------
__global__ __launch_bounds__(256) void pool_part(
    const float* __restrict__ h, float* __restrict__ ppart)
{
  const int b = blockIdx.y, d0 = blockIdx.x * 64, z = blockIdx.z;
  const int tid = threadIdx.x;
  const int dl = tid & 63, sg = tid >> 6;
  const int s0 = z * (S_ / PSPL_);
  float s = 0.f;
  #pragma unroll
  for (int si = sg; si < S_ / PSPL_; si += 4)
    s += h[((size_t)b * S_ + s0 + si) * D_ + d0 + dl];
  __shared__ float part[4][64];
  part[sg][dl] = s;
  __syncthreads();
  if (tid < 64) {
    const float v = part[0][tid] + part[1][tid] + part[2][tid] + part[3][tid];
    ppart[((size_t)z * B_ + b) * D_ + d0 + tid] = v;
  }
}

// Mean-pool stage 2: sum PSPL_ partials. grid (B*D/256).
__global__ __launch_bounds__(256) void pool_reduce(
    const float* __restrict__ ppart, float* __restrict__ pooled)
{
  const int idx = blockIdx.x * 256 + threadIdx.x;   // b*D + d
  float s = 0.f;
  #pragma unroll
  for (int z = 0; z < PSPL_; ++z)
    s += ppart[(size_t)z * B_ * D_ + idx];
  pooled[idx] = s * (1.0f / S_);
}

// classifier + aux: 1 block, 64 threads
__global__ __launch_bounds__(64) void cls_kernel(
    const float* __restrict__ pooled, const float* __restrict__ cls_w,
    const float* __restrict__ cls_b, const float* __restrict__ aux_acc,
    float* __restrict__ out)
{
  const int t = threadIdx.x;
  if (t < B_ * C_) {
    const int b = t >> 1, c = t & 1;
    float acc = cls_b[c];
    for (int d = 0; d < D_; ++d)
      acc = fmaf(pooled[b * D_ + d], cls_w[(size_t)d * C_ + c], acc);
    out[b * C_ + c] = acc;
  }
  if (t == 32) out[B_ * C_] = LBW_ * (*aux_acc);
}

// ------------------------------------------------------------------
extern "C" void kernel_launch(void* const* d_in, const int* in_sizes, int n_in,
                              void* d_out, int out_size, void* d_ws, size_t ws_size,
                              hipStream_t stream) {
  const float* x      = (const float*)d_in[0];
  const float* proj_w = (const float*)d_in[1];
  const float* proj_b = (const float*)d_in[2];
  const float* attn_w = (const float*)d_in[3];
  const float* attn_b = (const float*)d_in[4];
  const float* ln1_s  = (const float*)d_in[5];
  const float* ln1_b  = (const float*)d_in[6];
  const float* gate_w = (const float*)d_in[7];
  const float* gate_b = (const float*)d_in[8];
  const float* w1     = (const float*)d_in[9];
  const float* b1     = (const float*)d_in[10];
  const float* w2     = (const float*)d_in[11];
  const float* b2     = (const float*)d_in[12];
  const float* ln2_s  = (const float*)d_in[13];
  const float* ln2_b  = (const float*)d_in[14];
  const float* cls_w  = (const float*)d_in[15];
  const float* cls_b  = (const float*)d_in[16];
  float* out = (float*)d_out;

  // ---------------- workspace carve (bytes) ----------------
  char* base = (char*)d_ws;
  float* h      = (float*)base;                 base += (size_t)T_ * D_ * 4;
  float* t2     = (float*)base;                 base += (size_t)T_ * D_ * 4;
  float* ebuf   = (float*)base;                 base += (size_t)T_ * KTOP_ * D_ * 4;
  u16*   qkvb   = (u16*)base;                   base += (size_t)T_ * QLD_ * 2;
  u16*   x_bf   = (u16*)base;                   base += (size_t)T_ * IN_ * 2;
  u16*   h_bf   = (u16*)base;                   base += (size_t)T_ * D_ * 2;
  u16*   t1_bf  = (u16*)base;                   base += (size_t)T_ * D_ * 2;
  char*  big    = base;                         base += (size_t)T_ * KTOP_ * F_ * 2;
  u16*   wscr   = (u16*)base;                   base += (size_t)E_ * D_ * F_ * 2;
  float* topw   = (float*)base;                 base += (size_t)T_ * KTOP_ * 4;
  int*   counts_p = (int*)base;                 base += NBG_ * E_ * 4;
  float* routing_p= (float*)base;               base += NBG_ * E_ * 4;
  int*   blk_base = (int*)base;                 base += NBG_ * E_ * 4;
  int*   counts = (int*)base;                   base += E_ * 4;
  float* aux_acc= (float*)base;                 base += 4;
  int*   offsets= (int*)base;                   base += E_ * 4;
  int*   top_i  = (int*)base;                   base += (size_t)T_ * KTOP_ * 4;
  int*   idx_list=(int*)base;                   base += (size_t)T_ * KTOP_ * 4;
  int*   pos_tk = (int*)base;                   base += (size_t)T_ * KTOP_ * 4;
  float* pooled = (float*)base;                 base += (size_t)B_ * D_ * 4;
  float* ppart  = (float*)base;                 base += (size_t)PSPL_ * B_ * D_ * 4;

  u16* hbuf_bf = (u16*)big;   // [T*K][F] bf16 gelu acts

  // input cast + projection (+PE), writes h fp32 and h_bf bf16
  cast_x<<<(T_ * IN_) / 2048, 256, 0, stream>>>(x, x_bf);
  castT<<<dim3(D_/32, IN_/32, 1), 256, 0, stream>>>(proj_w, wscr, IN_, D_);
  gemm_gl<64, 1, 0, 1, 1, 0, 0><<<dim3(D_/64, T_/128), 256, 0, stream>>>(
      x_bf, wscr, proj_b, h, h_bf, D_, IN_, nullptr, nullptr, nullptr);

  for (int l = 0; l < L_; ++l) {
    // cast+transpose all 4 attention weight matrices -> wscr [2048][512]
    castT<<<dim3(D_/32, D_/32, 4), 256, 0, stream>>>(
        attn_w + (size_t)l*4*D_*D_, wscr, D_, D_);

    // fused QKV: N = 1536 (rows 0..1535 of wscr), bias = attn_b[l][0..1535]
    gemm_gl<128, 0, 0, 0, 1, 0, 0><<<dim3(QLD_/128, T_/128), 256, 0, stream>>>(
        h_bf, wscr, attn_b + (size_t)l*4*D_, nullptr, qkvb, QLD_, D_,
        nullptr, nullptr, nullptr);
    attn_mfma<<<dim3(S_/64, B_*H_), 256, 0, stream>>>(qkvb, t1_bf);
    // out-proj: WT rows 1536..2047
    gemm_gl<64, 0, 0, 1, 0, 0, 0><<<dim3(D_/64, T_/128), 256, 0, stream>>>(
        t1_bf, wscr + (size_t)3*D_*D_, attn_b + (size_t)(l*4+3)*D_, t2, nullptr,
        D_, D_, nullptr, nullptr, nullptr);
    ln_kernel<0><<<T_, 64, 0, stream>>>(h, h_bf, t2, nullptr, nullptr, nullptr,
                                        ln1_s + (size_t)l*D_, ln1_b + (size_t)l*D_);

    gate_kernel<<<NBG_, 256, 0, stream>>>(h, gate_w + (size_t)l*D_*E_,
                                          gate_b + (size_t)l*E_,
                                          top_i, topw, counts_p, routing_p);
    gate_scan<<<1, 64, 0, stream>>>(counts_p, routing_p, counts, offsets,
                                    blk_base, aux_acc, l == 0 ? 1 : 0);
    gate_fill<<<NBG_, 256, 0, stream>>>(top_i, blk_base, idx_list, pos_tk);

    castT<<<dim3(F_/32, D_/32, E_), 256, 0, stream>>>(
        w1 + (size_t)l*E_*D_*F_, wscr, D_, F_);
    gemm_gl<128, 0, 1, 0, 1, 1, 1><<<dim3(F_/128, (T_*KTOP_)/128, E_), 256, 0, stream>>>(
        h_bf, wscr, b1 + (size_t)l*E_*F_, nullptr, hbuf_bf,
        F_, D_, idx_list, offsets, counts);
    castT<<<dim3(D_/32, F_/32, E_), 256, 0, stream>>>(
        w2 + (size_t)l*E_*F_*D_, wscr, F_, D_);
    gemm_gl<128, 0, 0, 1, 0, 0, 1><<<dim3(D_/128, (T_*KTOP_)/128, E_), 256, 0, stream>>>(
        hbuf_bf, wscr, b2 + (size_t)l*E_*D_, ebuf, nullptr,
        D_, F_, idx_list, offsets, counts);
    ln_kernel<1><<<T_, 64, 0, stream>>>(h, h_bf, nullptr, ebuf, pos_tk, topw,
                                        ln2_s + (size_t)l*D_, ln2_b + (size_t)l*D_);
  }

  pool_part<<<dim3(D_/64, B_, PSPL_), 256, 0, stream>>>(h, ppart);
  pool_reduce<<<(B_*D_)/256, 256, 0, stream>>>(ppart, pooled);
  cls_kernel<<<1, 64, 0, stream>>>(pooled, cls_w, cls_b, aux_acc, out);
}

// Round 15
// 561.605 us; speedup vs baseline: 1.0393x; 1.0393x over previous
//
#include <hip/hip_runtime.h>
#include <math.h>

#define B_ 4
#define S_ 1024
#define IN_ 768
#define D_ 512
#define H_ 8
#define F_ 2048
#define E_ 8
#define KTOP_ 2
#define L_ 2
#define C_ 2
#define DH_ 64
#define T_ (B_*S_)   /* 4096 tokens */
#define EPS_ 1e-5f
#define LBW_ 0.01f
#define QLD_ (3*D_)  /* packed qkv row stride */
#define NBG_ (T_/256) /* gate blocks */
#define PSPL_ 16      /* pool S-splits */

typedef unsigned short u16;
typedef __attribute__((ext_vector_type(8))) unsigned short u16x8;
typedef __attribute__((ext_vector_type(4))) unsigned short u16x4;
typedef __attribute__((ext_vector_type(8))) short short8;
typedef __attribute__((ext_vector_type(4))) float f32x4;

__device__ __forceinline__ u16 f2b(float f) {
  union { float f; unsigned u; } v; v.f = f;
  const unsigned u = v.u;
  return (u16)((u + 0x7FFFu + ((u >> 16) & 1u)) >> 16);
}
__device__ __forceinline__ float b2f(u16 s) {
  union { unsigned u; float f; } v; v.u = ((unsigned)s) << 16;
  return v.f;
}

// async global->LDS, 16B per lane, LDS dest = wave-uniform base + lane*16
__device__ __forceinline__ void gl2lds16(const u16* g, u16* l) {
  __builtin_amdgcn_global_load_lds(
      (const __attribute__((address_space(1))) unsigned int*)g,
      (__attribute__((address_space(3))) unsigned int*)l, 16, 0, 0);
}

// ------------------------------------------------------------------
// Weight cast + transpose: W fp32 [K][N] -> WT bf16 [N][K], batched z.
// ------------------------------------------------------------------
__global__ __launch_bounds__(256) void castT(
    const float* __restrict__ W, u16* __restrict__ WT, int K, int N)
{
  __shared__ float tile[32][33];
  const size_t mo = (size_t)blockIdx.z * K * N;
  const int n0 = blockIdx.x * 32, k0 = blockIdx.y * 32;
  const int t = threadIdx.x;
  const int kr = t >> 3, nc4 = (t & 7) * 4;
  const float4 v = *(const float4*)(W + mo + (size_t)(k0 + kr) * N + n0 + nc4);
  tile[kr][nc4+0] = v.x; tile[kr][nc4+1] = v.y;
  tile[kr][nc4+2] = v.z; tile[kr][nc4+3] = v.w;
  __syncthreads();
  const int nr = t >> 3, kc4 = (t & 7) * 4;
  u16x4 o;
  #pragma unroll
  for (int i = 0; i < 4; ++i) o[i] = f2b(tile[kc4 + i][nr]);
  *(u16x4*)(WT + mo + (size_t)(n0 + nr) * K + k0 + kc4) = o;
}

// x fp32 -> bf16, elementwise (8/thread)
__global__ __launch_bounds__(256) void cast_x(
    const float* __restrict__ X, u16* __restrict__ Xb)
{
  const size_t i = ((size_t)blockIdx.x * 256 + threadIdx.x) * 8;
  const float4 a = *(const float4*)(X + i);
  const float4 b = *(const float4*)(X + i + 4);
  u16x8 o;
  o[0]=f2b(a.x); o[1]=f2b(a.y); o[2]=f2b(a.z); o[3]=f2b(a.w);
  o[4]=f2b(b.x); o[5]=f2b(b.y); o[6]=f2b(b.z); o[7]=f2b(b.w);
  *(u16x8*)(Xb + i) = o;
}

// ------------------------------------------------------------------
// MFMA GEMM (proven R13 single-buffer structure) + optional split-K.
// KSPLIT=2: blockIdx.z encodes (expert, ks) for MOE or ks for dense;
// each split computes K/2, writes partial rows offset by split index;
// bias added only by ks=0. Consumer (ln) sums the two halves.
// C[M,N] = A[M,K](bf16) @ WT[N,K]^T + bias. BM=128, 4 waves (2x2).
// ------------------------------------------------------------------
template<int BN, int PE, int GELU, int WF32, int WBF16, int GATHER, int MOE,
         int KSPLIT>
__global__ __launch_bounds__(256) void gemm_gl(
    const u16* __restrict__ A, const u16* __restrict__ WTb,
    const float* __restrict__ biasb, float* __restrict__ Cf,
    u16* __restrict__ Cb, int N, int K,
    const int* __restrict__ idx_list, const int* __restrict__ offsets,
    const int* __restrict__ counts)
{
  constexpr int BM = 128;
  constexpr int MI = 4;            // 64 rows / 16
  constexpr int MJ = BN / 32;      // (BN/2) / 16
  constexpr int NIB = BN / 32;     // B glds per wave
  constexpr int SROWS = MOE ? (T_ * KTOP_) : T_;  // split-row stride
  __shared__ __align__(16) u16 Atile[BM][64];
  __shared__ __align__(16) u16 Btile[BN][64];
  __shared__ int rowsrc[MOE ? BM : 1];

  const int tid = threadIdx.x;
  const int row0 = blockIdx.y * BM, col0 = blockIdx.x * BN;

  int ks = 0;
  int cnt = 0, off = 0;
  const u16* WT = WTb;
  const float* bias = biasb;
  if constexpr (MOE) {
    int e;
    if constexpr (KSPLIT == 2) { e = blockIdx.z >> 1; ks = blockIdx.z & 1; }
    else                       { e = blockIdx.z; }
    cnt = counts[e];
    if (row0 >= cnt) return;               // uniform exit, pre-barrier
    off = offsets[e];
    WT  = WTb + (size_t)e * K * N;
    bias = biasb + (size_t)e * N;
    if (tid < BM) {
      const int rr = row0 + tid;
      rowsrc[tid] = (rr < cnt) ? (GATHER ? idx_list[off + rr] : (off + rr)) : 0;
    }
    __syncthreads();
  } else {
    if constexpr (KSPLIT == 2) ks = blockIdx.z;
  }
  const int k_beg = ks * (K / KSPLIT);
  const int k_end = k_beg + (K / KSPLIT);

  const int w = tid >> 6, lane = tid & 63;
  const int q15 = lane & 15, g = lane >> 4;
  const int lrow8 = lane >> 3;                  // row within 8-row DMA chunk
  const int scol = ((lane & 7) ^ lrow8) * 8;    // pre-swizzled source col

  // per-lane staging source pointers
  const u16* aptr[4];
  #pragma unroll
  for (int t = 0; t < 4; ++t) {
    const int arow = w * 32 + t * 8 + lrow8;
    int grow;
    if constexpr (MOE) grow = rowsrc[arow];
    else               grow = row0 + arow;
    aptr[t] = A + (size_t)grow * K + scol;
  }
  const u16* bptr[NIB];
  #pragma unroll
  for (int t = 0; t < NIB; ++t) {
    const int brow = w * (BN / 4) + t * 8 + lrow8;
    bptr[t] = WT + (size_t)(col0 + brow) * K + scol;
  }

  const int ar0 = (w >> 1) * 64;
  const int bc0 = (w & 1) * (BN / 2);

  f32x4 acc[MI][MJ];
  #pragma unroll
  for (int i = 0; i < MI; ++i)
    #pragma unroll
    for (int j = 0; j < MJ; ++j) acc[i][j] = (f32x4){0.f, 0.f, 0.f, 0.f};

  for (int k0 = k_beg; k0 < k_end; k0 += 64) {
    #pragma unroll
    for (int t = 0; t < 4; ++t)
      gl2lds16(aptr[t] + k0, &Atile[w * 32 + t * 8][0]);
    #pragma unroll
    for (int t = 0; t < NIB; ++t)
      gl2lds16(bptr[t] + k0, &Btile[w * (BN / 4) + t * 8][0]);
    asm volatile("s_waitcnt vmcnt(0)" ::: "memory");
    __syncthreads();
    #pragma unroll
    for (int c = 0; c < 2; ++c) {
      const int ps = ((c * 4 + g) ^ (q15 & 7)) * 8;   // swizzled read slot
      short8 af[MI], bfv[MJ];
      #pragma unroll
      for (int i = 0; i < MI; ++i)
        af[i] = *(const short8*)&Atile[ar0 + i * 16 + q15][ps];
      #pragma unroll
      for (int j = 0; j < MJ; ++j)
        bfv[j] = *(const short8*)&Btile[bc0 + j * 16 + q15][ps];
      #pragma unroll
      for (int i = 0; i < MI; ++i)
        #pragma unroll
        for (int j = 0; j < MJ; ++j)
          acc[i][j] = __builtin_amdgcn_mfma_f32_16x16x32_bf16(af[i], bfv[j], acc[i][j], 0, 0, 0);
    }
    __syncthreads();
  }

  // ---- epilogue ----
  const size_t srow_off = (size_t)ks * SROWS;
  #pragma unroll
  for (int i = 0; i < MI; ++i) {
    #pragma unroll
    for (int r = 0; r < 4; ++r) {
      const int lrow = ar0 + i * 16 + g * 4 + r;
      if constexpr (MOE) {
        const int rr = row0 + lrow;
        if (rr >= cnt) continue;
        const size_t gidx = (size_t)off + rr + srow_off;
        #pragma unroll
        for (int j = 0; j < MJ; ++j) {
          const int c = col0 + bc0 + j * 16 + q15;
          float bv = bias[c];
          if (KSPLIT == 2 && ks == 1) bv = 0.f;
          float vv = acc[i][j][r] + bv;
          if (GELU) vv = 0.5f * vv * (1.0f + erff(vv * 0.7071067811865475f));
          if (WF32) Cf[gidx * N + c] = vv;
          if (WBF16) Cb[gidx * N + c] = f2b(vv);
        }
      } else {
        const size_t row = (size_t)(row0 + lrow) + srow_off;
        #pragma unroll
        for (int j = 0; j < MJ; ++j) {
          const int c = col0 + bc0 + j * 16 + q15;
          float bv = bias[c];
          if (KSPLIT == 2 && ks == 1) bv = 0.f;
          float vv = acc[i][j][r] + bv;
          if (PE) {
            const float kfac = -0.03597789207803197f;  // -2*ln(10000)/512
            const float div = expf((float)(c >> 1) * kfac);
            const float ang = (float)((row0 + lrow) & (S_ - 1)) * div;
            vv += (c & 1) ? cosf(ang) : sinf(ang);
          }
          if (WF32) Cf[row * N + c] = vv;
          if (WBF16) Cb[row * N + c] = f2b(vv);
        }
      }
    }
  }
}

// ------------------------------------------------------------------
// MFMA flash attention over packed qkv [T][1536]. grid (S/64, B*H).
// ------------------------------------------------------------------
__global__ __launch_bounds__(256) void attn_mfma(
    const u16* __restrict__ qkv, u16* __restrict__ og)
{
  __shared__ u16 Kl[32][72];
  __shared__ u16 VTl[64 * 34];
  const int qt = blockIdx.x;
  const int hh = blockIdx.y & 7, b = blockIdx.y >> 3;
  const int tid = threadIdx.x;
  const int w = tid >> 6, lane = tid & 63;
  const int g = lane >> 4, q15 = lane & 15;
  const int skv = tid >> 3, sd8 = (tid & 7) * 8;

  const size_t qrow = (size_t)(b * S_ + qt * 64 + w * 16 + q15) * QLD_ + hh * 64;
  const short8 qf0 = *(const short8*)(qkv + qrow + g * 8);
  const short8 qf1 = *(const short8*)(qkv + qrow + 32 + g * 8);

  f32x4 o0 = {0.f,0.f,0.f,0.f}, o1 = {0.f,0.f,0.f,0.f};
  f32x4 o2 = {0.f,0.f,0.f,0.f}, o3 = {0.f,0.f,0.f,0.f};
  float m = -1e30f, l = 0.f;

  for (int c0 = 0; c0 < S_; c0 += 32) {
    const size_t srow = (size_t)(b * S_ + c0 + skv) * QLD_ + hh * 64 + sd8;
    const u16x8 kv8 = *(const u16x8*)(qkv + srow + D_);
    const u16x8 vv8 = *(const u16x8*)(qkv + srow + 2 * D_);
    *(u16x8*)&Kl[skv][sd8] = kv8;
    #pragma unroll
    for (int j = 0; j < 8; ++j) {
      const int d = sd8 + j;
      const int kvp = skv ^ (((d >> 5) & 1) << 3);   // bank-decorrelated slot
      VTl[d * 34 + kvp] = vv8[j];
    }
    __syncthreads();

    f32x4 st0 = {0.f,0.f,0.f,0.f}, st1 = {0.f,0.f,0.f,0.f};
    {
      const short8 kf00 = *(const short8*)&Kl[q15][g * 8];
      const short8 kf01 = *(const short8*)&Kl[q15][32 + g * 8];
      const short8 kf10 = *(const short8*)&Kl[16 + q15][g * 8];
      const short8 kf11 = *(const short8*)&Kl[16 + q15][32 + g * 8];
      st0 = __builtin_amdgcn_mfma_f32_16x16x32_bf16(kf00, qf0, st0, 0, 0, 0);
      st0 = __builtin_amdgcn_mfma_f32_16x16x32_bf16(kf01, qf1, st0, 0, 0, 0);
      st1 = __builtin_amdgcn_mfma_f32_16x16x32_bf16(kf10, qf0, st1, 0, 0, 0);
      st1 = __builtin_amdgcn_mfma_f32_16x16x32_bf16(kf11, qf1, st1, 0, 0, 0);
    }

    float s0[4], s1[4];
    #pragma unroll
    for (int r = 0; r < 4; ++r) { s0[r] = st0[r] * 0.125f; s1[r] = st1[r] * 0.125f; }
    float cm = s0[0];
    #pragma unroll
    for (int r = 1; r < 4; ++r) cm = fmaxf(cm, s0[r]);
    #pragma unroll
    for (int r = 0; r < 4; ++r) cm = fmaxf(cm, s1[r]);
    cm = fmaxf(cm, __shfl_xor(cm, 16));
    cm = fmaxf(cm, __shfl_xor(cm, 32));
    const float mn = fmaxf(m, cm);
    const float rsc = __expf(m - mn);
    m = mn;
    float p0[4], p1[4];
    float rs = 0.f;
    #pragma unroll
    for (int r = 0; r < 4; ++r) { p0[r] = __expf(s0[r] - mn); rs += p0[r]; }
    #pragma unroll
    for (int r = 0; r < 4; ++r) { p1[r] = __expf(s1[r] - mn); rs += p1[r]; }
    rs += __shfl_xor(rs, 16);
    rs += __shfl_xor(rs, 32);
    l = l * rsc + rs;

    float rq[4];
    #pragma unroll
    for (int r = 0; r < 4; ++r) rq[r] = __shfl(rsc, 4 * g + r);
    #pragma unroll
    for (int r = 0; r < 4; ++r) {
      o0[r] *= rq[r]; o1[r] *= rq[r]; o2[r] *= rq[r]; o3[r] *= rq[r];
    }

    // pack (p0[r], p1[r]) -> bf16x2 once, shuffle the packed word (8 shfl)
    unsigned pk[4];
    #pragma unroll
    for (int r = 0; r < 4; ++r)
      asm("v_cvt_pk_bf16_f32 %0, %1, %2" : "=v"(pk[r]) : "v"(p0[r]), "v"(p1[r]));
    u16x8 pf;
    #pragma unroll
    for (int j = 0; j < 8; ++j) {
      const int src = q15 + 16 * ((j >> 2) + 2 * (g & 1));
      const unsigned pv = (unsigned)__shfl((int)pk[j & 3], src);
      pf[j] = (g >= 2) ? (u16)(pv >> 16) : (u16)(pv & 0xffffu);
    }
    const short8 pfs = *(const short8*)&pf;

    #pragma unroll
    for (int dt = 0; dt < 4; ++dt) {
      const int gsw = g ^ (dt >> 1);                 // read-side inverse swizzle
      const u16* vp = &VTl[(dt * 16 + q15) * 34 + 8 * gsw];
      union { unsigned u[4]; short8 s8; } yv;
      yv.u[0] = *(const unsigned*)(vp + 0);
      yv.u[1] = *(const unsigned*)(vp + 2);
      yv.u[2] = *(const unsigned*)(vp + 4);
      yv.u[3] = *(const unsigned*)(vp + 6);
      if (dt == 0) o0 = __builtin_amdgcn_mfma_f32_16x16x32_bf16(pfs, yv.s8, o0, 0, 0, 0);
      if (dt == 1) o1 = __builtin_amdgcn_mfma_f32_16x16x32_bf16(pfs, yv.s8, o1, 0, 0, 0);
      if (dt == 2) o2 = __builtin_amdgcn_mfma_f32_16x16x32_bf16(pfs, yv.s8, o2, 0, 0, 0);
      if (dt == 3) o3 = __builtin_amdgcn_mfma_f32_16x16x32_bf16(pfs, yv.s8, o3, 0, 0, 0);
    }
    __syncthreads();
  }

  const float linv = 1.0f / l;
  float lq[4];
  #pragma unroll
  for (int r = 0; r < 4; ++r) lq[r] = __shfl(linv, 4 * g + r);
  #pragma unroll
  for (int r = 0; r < 4; ++r) {
    const size_t tok = (size_t)(b * S_ + qt * 64 + w * 16 + 4 * g + r);
    u16* orow = og + tok * D_ + hh * 64 + q15;
    orow[0]  = f2b(o0[r] * lq[r]);
    orow[16] = f2b(o1[r] * lq[r]);
    orow[32] = f2b(o2[r] * lq[r]);
    orow[48] = f2b(o3[r] * lq[r]);
  }
}

__device__ __forceinline__ void load8(const float* p, float* a) {
  const float4 v0 = *(const float4*)p;
  const float4 v1 = *(const float4*)(p + 4);
  a[0]=v0.x; a[1]=v0.y; a[2]=v0.z; a[3]=v0.w;
  a[4]=v1.x; a[5]=v1.y; a[6]=v1.z; a[7]=v1.w;
}

// ------------------------------------------------------------------
// Fused residual + LayerNorm, in-place on h; also emits bf16 h.
// MODE0: h = LN(h + add0 + add1)   (split-K out-proj partials)
// MODE1: h = LN(h + w0*(e0a+e0b) + w1*(e1a+e1b))  (split-K gemm2)
// ------------------------------------------------------------------
template<int MODE>
__global__ __launch_bounds__(64) void ln_kernel(
    float* __restrict__ h, u16* __restrict__ hb,
    const float* __restrict__ add,
    const float* __restrict__ ebuf, const int* __restrict__ pos_tk,
    const float* __restrict__ topw,
    const float* __restrict__ sc, const float* __restrict__ bi)
{
  const int t = blockIdx.x;
  const int lane = threadIdx.x;
  const int d0 = lane * 8;
  float* hrow = h + (size_t)t * D_;
  float x[8];
  load8(hrow + d0, x);
  if (MODE == 0) {
    float a[8], a2[8];
    load8(add + (size_t)t * D_ + d0, a);
    load8(add + ((size_t)T_ + t) * D_ + d0, a2);
    #pragma unroll
    for (int i = 0; i < 8; ++i) x[i] += a[i] + a2[i];
  } else {
    const float w0 = topw[2*t], w1 = topw[2*t+1];
    const int p0 = pos_tk[2*t], p1 = pos_tk[2*t+1];
    const size_t SK = (size_t)T_ * KTOP_;
    float a[8], ab[8], b[8], bb[8];
    load8(ebuf + (size_t)p0 * D_ + d0, a);
    load8(ebuf + ((size_t)p0 + SK) * D_ + d0, ab);
    load8(ebuf + (size_t)p1 * D_ + d0, b);
    load8(ebuf + ((size_t)p1 + SK) * D_ + d0, bb);
    #pragma unroll
    for (int i = 0; i < 8; ++i) x[i] += w0 * (a[i] + ab[i]) + w1 * (b[i] + bb[i]);
  }
  float s = 0.f, ss = 0.f;
  #pragma unroll
  for (int i = 0; i < 8; ++i) { s += x[i]; ss += x[i] * x[i]; }
  #pragma unroll
  for (int off = 32; off > 0; off >>= 1) {
    s  += __shfl_xor(s,  off);
    ss += __shfl_xor(ss, off);
  }
  const float mu = s * (1.f / D_);
  const float var = ss * (1.f / D_) - mu * mu;
  const float rstd = rsqrtf(var + EPS_);
  float g[8], be[8];
  load8(sc + d0, g); load8(bi + d0, be);
  float y[8];
  #pragma unroll
  for (int i = 0; i < 8; ++i) y[i] = (x[i] - mu) * rstd * g[i] + be[i];
  float4 oo0, oo1;
  oo0.x=y[0]; oo0.y=y[1]; oo0.z=y[2]; oo0.w=y[3];
  oo1.x=y[4]; oo1.y=y[5]; oo1.z=y[6]; oo1.w=y[7];
  *(float4*)(hrow + d0) = oo0;
  *(float4*)(hrow + d0 + 4) = oo1;
  u16x8 ob;
  #pragma unroll
  for (int i = 0; i < 8; ++i) ob[i] = f2b(y[i]);
  *(u16x8*)(hb + (size_t)t * D_ + d0) = ob;
}

// ------------------------------------------------------------------
// Gate (fp32): softmax over E, top-2, renorm; per-block partials.
// ------------------------------------------------------------------
__global__ __launch_bounds__(256) void gate_kernel(
    const float* __restrict__ h, const float* __restrict__ gw,
    const float* __restrict__ gb,
    int* __restrict__ top_i, float* __restrict__ top_w,
    int* __restrict__ counts_p, float* __restrict__ routing_p)
{
  __shared__ float s_rout[E_];
  __shared__ int s_cnt[E_];
  const int tid = threadIdx.x;
  if (tid < E_) { s_rout[tid] = 0.f; s_cnt[tid] = 0; }
  __syncthreads();
  const int t = blockIdx.x * 256 + tid;
  const float* xr = h + (size_t)t * D_;
  float logit[E_] = {};
  for (int d = 0; d < D_; d += 4) {
    const float4 xv = *(const float4*)(xr + d);
    const float xs[4] = {xv.x, xv.y, xv.z, xv.w};
    #pragma unroll
    for (int i = 0; i < 4; ++i)
      #pragma unroll
      for (int e = 0; e < E_; ++e)
        logit[e] = fmaf(xs[i], gw[(size_t)(d+i) * E_ + e], logit[e]);
  }
  float mx = -1e30f;
  #pragma unroll
  for (int e = 0; e < E_; ++e) { logit[e] += gb[e]; mx = fmaxf(mx, logit[e]); }
  float p[E_]; float sum = 0.f;
  #pragma unroll
  for (int e = 0; e < E_; ++e) { p[e] = expf(logit[e] - mx); sum += p[e]; }
  const float inv = 1.0f / sum;
  #pragma unroll
  for (int e = 0; e < E_; ++e) p[e] *= inv;
  int i0 = 0; float v0 = p[0];
  #pragma unroll
  for (int e = 1; e < E_; ++e) if (p[e] > v0) { v0 = p[e]; i0 = e; }
  int i1 = -1; float v1 = -1.f;
  #pragma unroll
  for (int e = 0; e < E_; ++e) if (e != i0 && p[e] > v1) { v1 = p[e]; i1 = e; }
  const float sw = 1.0f / (v0 + v1);
  top_i[2*t] = i0; top_i[2*t+1] = i1;
  top_w[2*t] = v0 * sw; top_w[2*t+1] = v1 * sw;
  atomicAdd(&s_cnt[i0], 1); atomicAdd(&s_cnt[i1], 1);
  #pragma unroll
  for (int e = 0; e < E_; ++e) atomicAdd(&s_rout[e], p[e]);
  __syncthreads();
  if (tid < E_) {
    counts_p[blockIdx.x * E_ + tid] = s_cnt[tid];
    routing_p[blockIdx.x * E_ + tid] = s_rout[tid];
  }
}

// scan: totals, expert offsets, per-block bases, aux. 1 thread.
__global__ void gate_scan(
    const int* __restrict__ counts_p, const float* __restrict__ routing_p,
    int* __restrict__ counts, int* __restrict__ offsets,
    int* __restrict__ blk_base, float* __restrict__ aux_acc, int first)
{
  if (threadIdx.x == 0) {
    int cnt[E_]; float rout[E_];
    for (int e = 0; e < E_; ++e) { cnt[e] = 0; rout[e] = 0.f; }
    for (int b = 0; b < NBG_; ++b)
      for (int e = 0; e < E_; ++e) {
        cnt[e] += counts_p[b * E_ + e];
        rout[e] += routing_p[b * E_ + e];
      }
    int off = 0; float aux = 0.f;
    int run[E_];
    for (int e = 0; e < E_; ++e) {
      counts[e] = cnt[e];
      offsets[e] = off; run[e] = off; off += cnt[e];
      aux += ((float)cnt[e] / (float)(T_ * KTOP_)) * (rout[e] / (float)T_);
    }
    for (int b = 0; b < NBG_; ++b)
      for (int e = 0; e < E_; ++e) {
        blk_base[b * E_ + e] = run[e];
        run[e] += counts_p[b * E_ + e];
      }
    const float v = (float)E_ * aux;
    *aux_acc = first ? v : (*aux_acc + v);
  }
}

// fill: rank within block via LDS atomics + per-block base (no global atomics)
__global__ __launch_bounds__(256) void gate_fill(
    const int* __restrict__ top_i, const int* __restrict__ blk_base,
    int* __restrict__ idx_list, int* __restrict__ pos_tk)
{
  __shared__ int s_cur[E_];
  const int tid = threadIdx.x;
  if (tid < E_) s_cur[tid] = 0;
  __syncthreads();
  const int t = blockIdx.x * 256 + tid;
  const int e0 = top_i[2*t], e1 = top_i[2*t+1];
  const int r0 = atomicAdd(&s_cur[e0], 1);
  const int r1 = atomicAdd(&s_cur[e1], 1);
  const int g0 = blk_base[blockIdx.x * E_ + e0] + r0;
  const int g1 = blk_base[blockIdx.x * E_ + e1] + r1;
  idx_list[g0] = t; pos_tk[2*t]   = g0;
  idx_list[g1] = t; pos_tk[2*t+1] = g1;
}

// ------------------------------------------------------------------
// Mean-pool stage 1: grid (D/64, B, PSPL_); each block sums 64 S-rows.
// ------------------------------------------------------------------
__global__ __launch_bounds__(256) void pool_part(
    const float* __restrict__ h, float* __restrict__ ppart)
{
  const int b = blockIdx.y, d0 = blockIdx.x * 64, z = blockIdx.z;
  const int tid = threadIdx.x;
  const int dl = tid & 63, sg = tid >> 6;
  const int s0 = z * (S_ / PSPL_);
  float s = 0.f;
  #pragma unroll
  for (int si = sg; si < S_ / PSPL_; si += 4)
    s += h[((size_t)b * S_ + s0 + si) * D_ + d0 + dl];
  __shared__ float part[4][64];
  part[sg][dl] = s;
  __syncthreads();
  if (tid < 64) {
    const float v = part[0][tid] + part[1][tid] + part[2][tid] + part[3][tid];
    ppart[((size_t)z * B_ + b) * D_ + d0 + tid] = v;
  }
}

// Mean-pool stage 2: sum PSPL_ partials. grid (B*D/256).
__global__ __launch_bounds__(256) void pool_reduce(
    const float* __restrict__ ppart, float* __restrict__ pooled)
{
  const int idx = blockIdx.x * 256 + threadIdx.x;   // b*D + d
  float s = 0.f;
  #pragma unroll
  for (int z = 0; z < PSPL_; ++z)
    s += ppart[(size_t)z * B_ * D_ + idx];
  pooled[idx] = s * (1.0f / S_);
}

// classifier + aux: 1 block, 64 threads
__global__ __launch_bounds__(64) void cls_kernel(
    const float* __restrict__ pooled, const float* __restrict__ cls_w,
    const float* __restrict__ cls_b, const float* __restrict__ aux_acc,
    float* __restrict__ out)
{
  const int t = threadIdx.x;
  if (t < B_ * C_) {
    const int b = t >> 1, c = t & 1;
    float acc = cls_b[c];
    for (int d = 0; d < D_; ++d)
      acc = fmaf(pooled[b * D_ + d], cls_w[(size_t)d * C_ + c], acc);
    out[b * C_ + c] = acc;
  }
  if (t == 32) out[B_ * C_] = LBW_ * (*aux_acc);
}

// ------------------------------------------------------------------
extern "C" void kernel_launch(void* const* d_in, const int* in_sizes, int n_in,
                              void* d_out, int out_size, void* d_ws, size_t ws_size,
                              hipStream_t stream) {
  const float* x      = (const float*)d_in[0];
  const float* proj_w = (const float*)d_in[1];
  const float* proj_b = (const float*)d_in[2];
  const float* attn_w = (const float*)d_in[3];
  const float* attn_b = (const float*)d_in[4];
  const float* ln1_s  = (const float*)d_in[5];
  const float* ln1_b  = (const float*)d_in[6];
  const float* gate_w = (const float*)d_in[7];
  const float* gate_b = (const float*)d_in[8];
  const float* w1     = (const float*)d_in[9];
  const float* b1     = (const float*)d_in[10];
  const float* w2     = (const float*)d_in[11];
  const float* b2     = (const float*)d_in[12];
  const float* ln2_s  = (const float*)d_in[13];
  const float* ln2_b  = (const float*)d_in[14];
  const float* cls_w  = (const float*)d_in[15];
  const float* cls_b  = (const float*)d_in[16];
  float* out = (float*)d_out;

  // ---------------- workspace carve (bytes) ----------------
  char* base = (char*)d_ws;
  float* h      = (float*)base;                 base += (size_t)T_ * D_ * 4;
  float* t2     = (float*)base;                 base += (size_t)2 * T_ * D_ * 4;         // 2 K-splits
  float* ebuf   = (float*)base;                 base += (size_t)2 * T_ * KTOP_ * D_ * 4; // 2 K-splits
  u16*   qkvb   = (u16*)base;                   base += (size_t)T_ * QLD_ * 2;
  u16*   x_bf   = (u16*)base;                   base += (size_t)T_ * IN_ * 2;
  u16*   h_bf   = (u16*)base;                   base += (size_t)T_ * D_ * 2;
  u16*   t1_bf  = (u16*)base;                   base += (size_t)T_ * D_ * 2;
  char*  big    = base;                         base += (size_t)T_ * KTOP_ * F_ * 2;
  u16*   wscr   = (u16*)base;                   base += (size_t)E_ * D_ * F_ * 2;
  float* topw   = (float*)base;                 base += (size_t)T_ * KTOP_ * 4;
  int*   counts_p = (int*)base;                 base += NBG_ * E_ * 4;
  float* routing_p= (float*)base;               base += NBG_ * E_ * 4;
  int*   blk_base = (int*)base;                 base += NBG_ * E_ * 4;
  int*   counts = (int*)base;                   base += E_ * 4;
  float* aux_acc= (float*)base;                 base += 4;
  int*   offsets= (int*)base;                   base += E_ * 4;
  int*   top_i  = (int*)base;                   base += (size_t)T_ * KTOP_ * 4;
  int*   idx_list=(int*)base;                   base += (size_t)T_ * KTOP_ * 4;
  int*   pos_tk = (int*)base;                   base += (size_t)T_ * KTOP_ * 4;
  float* pooled = (float*)base;                 base += (size_t)B_ * D_ * 4;
  float* ppart  = (float*)base;                 base += (size_t)PSPL_ * B_ * D_ * 4;

  u16* hbuf_bf = (u16*)big;   // [T*K][F] bf16 gelu acts

  // input cast + projection (+PE), writes h fp32 and h_bf bf16
  cast_x<<<(T_ * IN_) / 2048, 256, 0, stream>>>(x, x_bf);
  castT<<<dim3(D_/32, IN_/32, 1), 256, 0, stream>>>(proj_w, wscr, IN_, D_);
  gemm_gl<64, 1, 0, 1, 1, 0, 0, 1><<<dim3(D_/64, T_/128), 256, 0, stream>>>(
      x_bf, wscr, proj_b, h, h_bf, D_, IN_, nullptr, nullptr, nullptr);

  for (int l = 0; l < L_; ++l) {
    // cast+transpose all 4 attention weight matrices -> wscr [2048][512]
    castT<<<dim3(D_/32, D_/32, 4), 256, 0, stream>>>(
        attn_w + (size_t)l*4*D_*D_, wscr, D_, D_);

    // fused QKV: N = 1536 (rows 0..1535 of wscr), bias = attn_b[l][0..1535]
    gemm_gl<128, 0, 0, 0, 1, 0, 0, 1><<<dim3(QLD_/128, T_/128), 256, 0, stream>>>(
        h_bf, wscr, attn_b + (size_t)l*4*D_, nullptr, qkvb, QLD_, D_,
        nullptr, nullptr, nullptr);
    attn_mfma<<<dim3(S_/64, B_*H_), 256, 0, stream>>>(qkvb, t1_bf);
    // out-proj, split-K=2: partials to t2[0..T) and t2[T..2T)
    gemm_gl<64, 0, 0, 1, 0, 0, 0, 2><<<dim3(D_/64, T_/128, 2), 256, 0, stream>>>(
        t1_bf, wscr + (size_t)3*D_*D_, attn_b + (size_t)(l*4+3)*D_, t2, nullptr,
        D_, D_, nullptr, nullptr, nullptr);
    ln_kernel<0><<<T_, 64, 0, stream>>>(h, h_bf, t2, nullptr, nullptr, nullptr,
                                        ln1_s + (size_t)l*D_, ln1_b + (size_t)l*D_);

    gate_kernel<<<NBG_, 256, 0, stream>>>(h, gate_w + (size_t)l*D_*E_,
                                          gate_b + (size_t)l*E_,
                                          top_i, topw, counts_p, routing_p);
    gate_scan<<<1, 64, 0, stream>>>(counts_p, routing_p, counts, offsets,
                                    blk_base, aux_acc, l == 0 ? 1 : 0);
    gate_fill<<<NBG_, 256, 0, stream>>>(top_i, blk_base, idx_list, pos_tk);

    castT<<<dim3(F_/32, D_/32, E_), 256, 0, stream>>>(
        w1 + (size_t)l*E_*D_*F_, wscr, D_, F_);
    gemm_gl<128, 0, 1, 0, 1, 1, 1, 1><<<dim3(F_/128, (T_*KTOP_)/128, E_), 256, 0, stream>>>(
        h_bf, wscr, b1 + (size_t)l*E_*F_, nullptr, hbuf_bf,
        F_, D_, idx_list, offsets, counts);
    castT<<<dim3(D_/32, F_/32, E_), 256, 0, stream>>>(
        w2 + (size_t)l*E_*F_*D_, wscr, F_, D_);
    // gemm2, split-K=2: z = (expert<<1)|ks; partials to ebuf halves
    gemm_gl<128, 0, 0, 1, 0, 0, 1, 2><<<dim3(D_/128, (T_*KTOP_)/128, 2*E_), 256, 0, stream>>>(
        hbuf_bf, wscr, b2 + (size_t)l*E_*D_, ebuf, nullptr,
        D_, F_, idx_list, offsets, counts);
    ln_kernel<1><<<T_, 64, 0, stream>>>(h, h_bf, nullptr, ebuf, pos_tk, topw,
                                        ln2_s + (size_t)l*D_, ln2_b + (size_t)l*D_);
  }

  pool_part<<<dim3(D_/64, B_, PSPL_), 256, 0, stream>>>(h, ppart);
  pool_reduce<<<(B_*D_)/256, 256, 0, stream>>>(ppart, pooled);
  cls_kernel<<<1, 64, 0, stream>>>(pooled, cls_w, cls_b, aux_acc, out);
}